// Round 1
// baseline (265.243 us; speedup 1.0000x reference)
//
#include <hip/hip_runtime.h>
#include <math.h>

#define N_NODES   30000
#define N_EDGE    300000
#define N_EDGE_T  330000   // + self loops
#define HEADS     8
#define HIDDEN    64
#define IN_DIM    8
#define OUT_DIM   8
#define NEG_SLOPE 0.2f

// Opaque def: value now originates from asm -> cannot be rematerialized by
// re-loading; forces it to stay VGPR-resident across the loop.
#define PIN_V(v) asm volatile("" : "+v"(v))

// ---- DPP cross-lane reductions (pure VALU; no lgkmcnt, unlike ds_swizzle) ----
// R4 theory: in-loop __shfl_xor (DS pipe) shares lgkmcnt with the s_load
// prefetch; SMEM is out-of-order so every shuffle forced lgkmcnt(0), draining
// the prefetch each iteration. DPP removes all DS ops from the loop.
#define DPP_ADDF(x, ctrl)                                                     \
    x += __int_as_float(__builtin_amdgcn_update_dpp(                          \
            0, __float_as_int(x), (ctrl), 0xF, 0xF, true))
// sum over aligned 16-lane group (all 16 lanes get the total):
// xor1 (quad_perm 1,0,3,2) ; xor2 (quad_perm 2,3,0,1) ; 8-half mirror ; row mirror
#define RED16(x) do { DPP_ADDF(x, 0xB1); DPP_ADDF(x, 0x4E);                   \
                      DPP_ADDF(x, 0x141); DPP_ADDF(x, 0x140); } while (0)
// sum over aligned 8-lane group:
#define RED8(x)  do { DPP_ADDF(x, 0xB1); DPP_ADDF(x, 0x4E);                   \
                      DPP_ADDF(x, 0x141); } while (0)

__device__ __forceinline__ float rfl_f(float v) {
    return __int_as_float(__builtin_amdgcn_readfirstlane(__float_as_int(v)));
}

// ---------------- CSR build ----------------

__global__ __launch_bounds__(256) void zero_kernel(int* __restrict__ count) {
    int i = blockIdx.x * 256 + threadIdx.x;
    if (i < N_NODES) count[i] = 0;
}

__global__ __launch_bounds__(256) void count_kernel(const int* __restrict__ ei,
                                                    int* __restrict__ count) {
    int e = blockIdx.x * 256 + threadIdx.x;
    if (e >= N_EDGE_T) return;
    int d = (e < N_EDGE) ? ei[N_EDGE + e] : (e - N_EDGE);
    atomicAdd(&count[d], 1);
}

// Single-block scan, 8 ints/thread via 2x int4: 4 rounds.
__global__ __launch_bounds__(1024) void scan_kernel(const int* __restrict__ count,
                                                    int* __restrict__ row_start,
                                                    int* __restrict__ cursor) {
    __shared__ int wsum[16];
    const int tid  = threadIdx.x;
    const int wave = tid >> 6;
    const int lane = tid & 63;
    const int4* c4 = (const int4*)count;
    const int N4 = N_NODES / 4;              // 7500 int4s exactly
    int run = 0;
    for (int r = 0; r < 4; ++r) {
        const int g  = r * 1024 + tid;       // thread-slot in round
        const int i0 = 2 * g;                // int4 idx of first half
        const int i1 = 2 * g + 1;
        int4 v0 = make_int4(0,0,0,0), v1 = make_int4(0,0,0,0);
        if (i0 < N4) v0 = c4[i0];
        if (i1 < N4) v1 = c4[i1];
        int s = v0.x + v0.y + v0.z + v0.w + v1.x + v1.y + v1.z + v1.w;
        int sc = s;
        #pragma unroll
        for (int off = 1; off < 64; off <<= 1) {
            int t = __shfl_up(sc, off, 64);
            if (lane >= off) sc += t;
        }
        if (lane == 63) wsum[wave] = sc;
        __syncthreads();
        if (tid < 16) {
            int w = wsum[tid];
            #pragma unroll
            for (int off = 1; off < 16; off <<= 1) {
                int t = __shfl_up(w, off, 64);
                if (tid >= off) w += t;
            }
            wsum[tid] = w;
        }
        __syncthreads();
        const int woff = (wave > 0) ? wsum[wave - 1] : 0;
        int e0 = run + woff + (sc - s);       // exclusive prefix of this thread's 8
        int4 ex0, ex1;
        ex0.x = e0;           ex0.y = ex0.x + v0.x;
        ex0.z = ex0.y + v0.y; ex0.w = ex0.z + v0.z;
        int e4 = ex0.w + v0.w;
        ex1.x = e4;           ex1.y = ex1.x + v1.x;
        ex1.z = ex1.y + v1.y; ex1.w = ex1.z + v1.z;
        if (i0 < N4) { ((int4*)row_start)[i0] = ex0; ((int4*)cursor)[i0] = ex0; }
        if (i1 < N4) { ((int4*)row_start)[i1] = ex1; ((int4*)cursor)[i1] = ex1; }
        const int tot = wsum[15];
        __syncthreads();
        run += tot;
    }
    if (tid == 0) row_start[N_NODES] = run;
}

__global__ __launch_bounds__(256) void scatter_kernel(const int* __restrict__ ei,
                                                      int* __restrict__ cursor,
                                                      int* __restrict__ edge_src) {
    int e = blockIdx.x * 256 + threadIdx.x;
    if (e >= N_EDGE_T) return;
    int s, d;
    if (e < N_EDGE) { s = ei[e]; d = ei[N_EDGE + e]; }
    else            { s = d = e - N_EDGE; }
    int pos = atomicAdd(&cursor[d], 1);
    edge_src[pos] = s;
}

// ---------------- Layer 1 ----------------
// Block = 128 threads = 2 waves per dst node. 16 lanes per head:
// head = tid>>4, c4 = tid&15 -> 4 channels colb..colb+3.
// R4 restructure:
//  - logit reduce via DPP (no DS ops in loop -> lgkm waits only for s_loads)
//  - 4-edge groups; next-group idx loads issued before edges 0,1; next-group
//    row loads issued before edges 2,3 -> every lgkm drain waits only on
//    loads issued >= one compute-block (~220 cyc) earlier
//  - v-space accumulation: v starts at xr; acc' = sum p*v; epilogue does
//    acc = acc'*inv - xr (exact algebra, saves 4 adds/edge)
//  - amdgpu_waves_per_eu(4,6): stop allocator from starving to 32 VGPRs and
//    re-loading weights in-loop (R3 symptom: VGPR_Count=32 with 40+ pins)

__global__ void __launch_bounds__(128)
__attribute__((amdgpu_waves_per_eu(4, 6)))
layer1_kernel(
    const float* __restrict__ x,
    const float* __restrict__ W1l, const float* __restrict__ W1r,
    const float* __restrict__ a1,  const float* __restrict__ b1,
    const float* __restrict__ W2l, const float* __restrict__ W2r,
    const int* __restrict__ row_start, const int* __restrict__ edge_src,
    float* __restrict__ xl2, float* __restrict__ xr2)
{
    const int d    = blockIdx.x;
    const int tid  = threadIdx.x;        // 0..127
    const int head = tid >> 4;           // 0..7 (heads 0-3 wave0, 4-7 wave1)
    const int c4   = tid & 15;
    const int colb = head * HIDDEN + c4 * 4;   // 4 contiguous columns

    float wl[IN_DIM][4], av[4];
    #pragma unroll
    for (int k = 0; k < IN_DIM; ++k) {
        const float4 l4 = *(const float4*)&W1l[k * 512 + colb];
        wl[k][0] = l4.x; wl[k][1] = l4.y; wl[k][2] = l4.z; wl[k][3] = l4.w;
    }
    { const float4 a4 = *(const float4*)&a1[colb];
      av[0] = a4.x; av[1] = a4.y; av[2] = a4.z; av[3] = a4.w; }

    // xr for destination node; W1r streamed (not kept resident)
    float xr[4] = {0.f, 0.f, 0.f, 0.f};
    #pragma unroll
    for (int k = 0; k < IN_DIM; ++k) {
        const float4 r4 = *(const float4*)&W1r[k * 512 + colb];
        const float xv = x[d * IN_DIM + k];
        xr[0] = fmaf(xv, r4.x, xr[0]); xr[1] = fmaf(xv, r4.y, xr[1]);
        xr[2] = fmaf(xv, r4.z, xr[2]); xr[3] = fmaf(xv, r4.w, xr[3]);
    }

    #pragma unroll
    for (int k = 0; k < IN_DIM; ++k) {
        PIN_V(wl[k][0]); PIN_V(wl[k][1]); PIN_V(wl[k][2]); PIN_V(wl[k][3]);
    }
    PIN_V(av[0]); PIN_V(av[1]); PIN_V(av[2]); PIN_V(av[3]);
    PIN_V(xr[0]); PIN_V(xr[1]); PIN_V(xr[2]); PIN_V(xr[3]);

    const int rs = row_start[d];
    const int re = row_start[d + 1];

    float denom  = 0.f;
    float acc[4] = {0.f, 0.f, 0.f, 0.f};   // acc' = sum p * (xl + xr)

    // two edges at a time, interleaved chains; v starts at xr (v-space)
    auto pair2 = [&](const float (&ra)[IN_DIM], const float (&rb)[IN_DIM],
                     bool va, bool vb) {
        float v0a = xr[0], v1a = xr[1], v2a = xr[2], v3a = xr[3];
        float v0b = xr[0], v1b = xr[1], v2b = xr[2], v3b = xr[3];
        #pragma unroll
        for (int k = 0; k < IN_DIM; ++k) {
            const float xa = ra[k], xb = rb[k];
            v0a = fmaf(xa, wl[k][0], v0a); v0b = fmaf(xb, wl[k][0], v0b);
            v1a = fmaf(xa, wl[k][1], v1a); v1b = fmaf(xb, wl[k][1], v1b);
            v2a = fmaf(xa, wl[k][2], v2a); v2b = fmaf(xb, wl[k][2], v2b);
            v3a = fmaf(xa, wl[k][3], v3a); v3b = fmaf(xb, wl[k][3], v3b);
        }
        float ta, tb, ea, eb;
        ta = fmaxf(v0a, NEG_SLOPE * v0a); ea = av[0] * ta;
        tb = fmaxf(v0b, NEG_SLOPE * v0b); eb = av[0] * tb;
        ta = fmaxf(v1a, NEG_SLOPE * v1a); ea = fmaf(av[1], ta, ea);
        tb = fmaxf(v1b, NEG_SLOPE * v1b); eb = fmaf(av[1], tb, eb);
        ta = fmaxf(v2a, NEG_SLOPE * v2a); ea = fmaf(av[2], ta, ea);
        tb = fmaxf(v2b, NEG_SLOPE * v2b); eb = fmaf(av[2], tb, eb);
        ta = fmaxf(v3a, NEG_SLOPE * v3a); ea = fmaf(av[3], ta, ea);
        tb = fmaxf(v3b, NEG_SLOPE * v3b); eb = fmaf(av[3], tb, eb);
        RED16(ea); RED16(eb);                     // pure VALU, no lgkm
        float pa = va ? __expf(ea) : 0.f;
        float pb = vb ? __expf(eb) : 0.f;
        denom += pa + pb;
        acc[0] = fmaf(pb, v0b, fmaf(pa, v0a, acc[0]));
        acc[1] = fmaf(pb, v1b, fmaf(pa, v1a, acc[1]));
        acc[2] = fmaf(pb, v2b, fmaf(pa, v2a, acc[2]));
        acc[3] = fmaf(pb, v3b, fmaf(pa, v3a, acc[3]));
    };

    // group 0: indices + rows (uniform -> s_load; readfirstlane keeps SGPR)
    float row[4][IN_DIM];
    {
        int s0, s1, s2, s3, e;
        e = rs;                            s0 = __builtin_amdgcn_readfirstlane(edge_src[e]);
        e = rs + 1; if (e >= re) e = re-1; s1 = __builtin_amdgcn_readfirstlane(edge_src[e]);
        e = rs + 2; if (e >= re) e = re-1; s2 = __builtin_amdgcn_readfirstlane(edge_src[e]);
        e = rs + 3; if (e >= re) e = re-1; s3 = __builtin_amdgcn_readfirstlane(edge_src[e]);
        #pragma unroll
        for (int k = 0; k < IN_DIM; ++k) {
            row[0][k] = rfl_f(x[s0 * IN_DIM + k]);
            row[1][k] = rfl_f(x[s1 * IN_DIM + k]);
            row[2][k] = rfl_f(x[s2 * IN_DIM + k]);
            row[3][k] = rfl_f(x[s3 * IN_DIM + k]);
        }
    }

    int base = rs;
    for (;;) {
        const int  nbase = base + 4;
        const bool more  = nbase < re;

        // issue next-group index loads; their lgkm drain lands after edges 0,1
        int ns0 = 0, ns1 = 0, ns2 = 0, ns3 = 0;
        if (more) {
            int e;
            e = nbase;                            ns0 = __builtin_amdgcn_readfirstlane(edge_src[e]);
            e = nbase + 1; if (e >= re) e = re-1; ns1 = __builtin_amdgcn_readfirstlane(edge_src[e]);
            e = nbase + 2; if (e >= re) e = re-1; ns2 = __builtin_amdgcn_readfirstlane(edge_src[e]);
            e = nbase + 3; if (e >= re) e = re-1; ns3 = __builtin_amdgcn_readfirstlane(edge_src[e]);
        }

        pair2(row[0], row[1], true, base + 1 < re);

        // issue next-group row loads; drained at next iteration's pair2
        float nrow[4][IN_DIM];
        if (more) {
            #pragma unroll
            for (int k = 0; k < IN_DIM; ++k) {
                nrow[0][k] = rfl_f(x[ns0 * IN_DIM + k]);
                nrow[1][k] = rfl_f(x[ns1 * IN_DIM + k]);
                nrow[2][k] = rfl_f(x[ns2 * IN_DIM + k]);
                nrow[3][k] = rfl_f(x[ns3 * IN_DIM + k]);
            }
        }

        pair2(row[2], row[3], base + 2 < re, base + 3 < re);

        if (!more) break;
        base = nbase;
        #pragma unroll
        for (int k = 0; k < IN_DIM; ++k) {
            row[0][k] = nrow[0][k]; row[1][k] = nrow[1][k];
            row[2][k] = nrow[2][k]; row[3][k] = nrow[3][k];
        }
    }

    const float inv = 1.f / denom;
    const float4 b4 = *(const float4*)&b1[colb];
    float hv[4];
    // acc'/denom - xr = true attention output; then +bias, ReLU
    hv[0] = fmaxf(fmaf(acc[0], inv, b4.x - xr[0]), 0.f);
    hv[1] = fmaxf(fmaf(acc[1], inv, b4.y - xr[1]), 0.f);
    hv[2] = fmaxf(fmaf(acc[2], inv, b4.z - xr[2]), 0.f);
    hv[3] = fmaxf(fmaf(acc[3], inv, b4.w - xr[3]), 0.f);

    // Epilogue: per-lane partials of h @ W2{l,r}, DPP-reduce over 16-lane
    // group, LDS finish across heads.
    float vl[OUT_DIM], vr[OUT_DIM];
    #pragma unroll
    for (int j = 0; j < OUT_DIM; ++j) { vl[j] = 0.f; vr[j] = 0.f; }
    #pragma unroll
    for (int i = 0; i < 4; ++i) {
        const float4 l0 = *(const float4*)&W2l[(colb + i) * OUT_DIM];
        const float4 l1 = *(const float4*)&W2l[(colb + i) * OUT_DIM + 4];
        const float4 r0 = *(const float4*)&W2r[(colb + i) * OUT_DIM];
        const float4 r1 = *(const float4*)&W2r[(colb + i) * OUT_DIM + 4];
        vl[0] = fmaf(hv[i], l0.x, vl[0]); vl[1] = fmaf(hv[i], l0.y, vl[1]);
        vl[2] = fmaf(hv[i], l0.z, vl[2]); vl[3] = fmaf(hv[i], l0.w, vl[3]);
        vl[4] = fmaf(hv[i], l1.x, vl[4]); vl[5] = fmaf(hv[i], l1.y, vl[5]);
        vl[6] = fmaf(hv[i], l1.z, vl[6]); vl[7] = fmaf(hv[i], l1.w, vl[7]);
        vr[0] = fmaf(hv[i], r0.x, vr[0]); vr[1] = fmaf(hv[i], r0.y, vr[1]);
        vr[2] = fmaf(hv[i], r0.z, vr[2]); vr[3] = fmaf(hv[i], r0.w, vr[3]);
        vr[4] = fmaf(hv[i], r1.x, vr[4]); vr[5] = fmaf(hv[i], r1.y, vr[5]);
        vr[6] = fmaf(hv[i], r1.z, vr[6]); vr[7] = fmaf(hv[i], r1.w, vr[7]);
    }
    #pragma unroll
    for (int j = 0; j < OUT_DIM; ++j) { RED16(vl[j]); RED16(vr[j]); }

    __shared__ float psl[HEADS][OUT_DIM];
    __shared__ float psr[HEADS][OUT_DIM];
    if (c4 == 0) {
        #pragma unroll
        for (int j = 0; j < OUT_DIM; ++j) { psl[head][j] = vl[j]; psr[head][j] = vr[j]; }
    }
    __syncthreads();
    if (tid < 16) {
        const int side = tid >> 3, j = tid & 7;
        float s = 0.f;
        if (side == 0) {
            #pragma unroll
            for (int h = 0; h < HEADS; ++h) s += psl[h][j];
            xl2[d * OUT_DIM + j] = s;
        } else {
            #pragma unroll
            for (int h = 0; h < HEADS; ++h) s += psr[h][j];
            xr2[d * OUT_DIM + j] = s;
        }
    }
}

// ---------------- Layer 2 (1 head, dim 8) ----------------

__global__ __launch_bounds__(256) void layer2_kernel(
    const float* __restrict__ xl2, const float* __restrict__ xr2,
    const float* __restrict__ a2,  const float* __restrict__ b2,
    const int* __restrict__ row_start, const int* __restrict__ edge_src,
    float* __restrict__ out)
{
    const int wave = threadIdx.x >> 6;
    const int lane = threadIdx.x & 63;
    const int d = blockIdx.x * 4 + wave;
    if (d >= N_NODES) return;
    const int sub = lane >> 3;   // edge slot 0..7
    const int c   = lane & 7;    // channel

    const float a_c  = a2[c];
    const float xr_d = xr2[d * OUT_DIM + c];

    const int rs = row_start[d];
    const int re = row_start[d + 1];

    float denom = 0.f, acc = 0.f;

    for (int base = rs; base < re; base += 8) {
        int e = base + sub;
        bool valid = (e < re);
        int s = valid ? edge_src[e] : 0;
        float xls = xl2[s * OUT_DIM + c];
        float v = xls + xr_d;
        float t = fmaxf(v, NEG_SLOPE * v);
        float eh = a_c * t;
        RED8(eh);                       // DPP: no lgkm in loop (was 3x shfl_xor)
        float p = valid ? __expf(eh) : 0.f;
        denom += p;
        acc = fmaf(p, xls, acc);
    }

    denom += __shfl_xor(denom, 8,  64);  acc += __shfl_xor(acc, 8,  64);
    denom += __shfl_xor(denom, 16, 64);  acc += __shfl_xor(acc, 16, 64);
    denom += __shfl_xor(denom, 32, 64);  acc += __shfl_xor(acc, 32, 64);

    if (sub == 0) out[d * OUT_DIM + c] = acc / denom + b2[c];
}

// ---------------- launch ----------------

extern "C" void kernel_launch(void* const* d_in, const int* in_sizes, int n_in,
                              void* d_out, int out_size, void* d_ws, size_t ws_size,
                              hipStream_t stream) {
    const float* x   = (const float*)d_in[0];
    const int*   ei  = (const int*)  d_in[1];
    const float* W1l = (const float*)d_in[2];
    const float* W1r = (const float*)d_in[3];
    const float* a1  = (const float*)d_in[4];
    const float* b1  = (const float*)d_in[5];
    const float* W2l = (const float*)d_in[6];
    const float* W2r = (const float*)d_in[7];
    const float* a2  = (const float*)d_in[8];
    const float* b2  = (const float*)d_in[9];
    float* out = (float*)d_out;

    char* ws = (char*)d_ws;
    size_t off = 0;
    auto carve = [&](size_t bytes) { char* p = ws + off; off += (bytes + 255) & ~size_t(255); return p; };
    int*   count     = (int*)  carve(N_NODES * sizeof(int));
    int*   row_start = (int*)  carve((N_NODES + 1) * sizeof(int));
    int*   cursor    = (int*)  carve(N_NODES * sizeof(int));
    int*   edge_src  = (int*)  carve(N_EDGE_T * sizeof(int));
    float* xl2       = (float*)carve(N_NODES * OUT_DIM * sizeof(float));
    float* xr2       = (float*)carve(N_NODES * OUT_DIM * sizeof(float));

    zero_kernel   <<<(N_NODES  + 255) / 256, 256, 0, stream>>>(count);
    count_kernel  <<<(N_EDGE_T + 255) / 256, 256, 0, stream>>>(ei, count);
    scan_kernel   <<<1, 1024, 0, stream>>>(count, row_start, cursor);
    scatter_kernel<<<(N_EDGE_T + 255) / 256, 256, 0, stream>>>(ei, cursor, edge_src);
    layer1_kernel <<<N_NODES, 128, 0, stream>>>(x, W1l, W1r, a1, b1, W2l, W2r,
                                                row_start, edge_src, xl2, xr2);
    layer2_kernel <<<(N_NODES + 3) / 4, 256, 0, stream>>>(xl2, xr2, a2, b2,
                                                          row_start, edge_src, out);
}